// Round 1
// baseline (558.545 us; speedup 1.0000x reference)
//
#include <hip/hip_runtime.h>
#include <math.h>

#define Bn 4
#define Cn 32
#define Dn 64
#define Hn 64
#define Wn 64
#define DHW (Dn * Hn * Wn)      /* 262144 */
#define TOT (Bn * Cn * DHW)     /* 33554432 */

// ---- order-preserving float<->uint map for atomic max ----
__device__ __forceinline__ unsigned fmap(float f) {
    unsigned u = __float_as_uint(f);
    return (u & 0x80000000u) ? ~u : (u | 0x80000000u);
}
__device__ __forceinline__ float funmap(unsigned u) {
    return (u & 0x80000000u) ? __uint_as_float(u & 0x7fffffffu)
                             : __uint_as_float(~u);
}

// ============================================================
// Kernel 1: fused reductions.
//  - per (b, spatial): mean & max over C  -> s_avg, s_max  [B,DHW]
//  - per (b, c):      sum & max over DHW -> ch_sum, ch_max [B,C] (atomics)
// grid: B * (DHW/1024) blocks, 256 threads, float4 per thread
// ============================================================
__global__ __launch_bounds__(256) void reduce_kernel(
    const float* __restrict__ x,
    float* __restrict__ s_avg, float* __restrict__ s_max,
    float* __restrict__ ch_sum, unsigned* __restrict__ ch_max) {
    const int blocks_per_b = DHW / 1024;  // 256
    const int b = blockIdx.x / blocks_per_b;
    const int chunk = blockIdx.x % blocks_per_b;
    const int base = chunk * 1024 + threadIdx.x * 4;
    const int lane = threadIdx.x & 63;

    float4 ssum = make_float4(0.f, 0.f, 0.f, 0.f);
    float4 smax = make_float4(-INFINITY, -INFINITY, -INFINITY, -INFINITY);

#pragma unroll 1
    for (int c = 0; c < Cn; ++c) {
        const float4 v = *reinterpret_cast<const float4*>(
            x + (size_t)(b * Cn + c) * DHW + base);
        ssum.x += v.x; ssum.y += v.y; ssum.z += v.z; ssum.w += v.w;
        smax.x = fmaxf(smax.x, v.x); smax.y = fmaxf(smax.y, v.y);
        smax.z = fmaxf(smax.z, v.z); smax.w = fmaxf(smax.w, v.w);

        float ps = v.x + v.y + v.z + v.w;
        float pm = fmaxf(fmaxf(v.x, v.y), fmaxf(v.z, v.w));
#pragma unroll
        for (int off = 32; off; off >>= 1) {
            ps += __shfl_xor(ps, off);
            pm = fmaxf(pm, __shfl_xor(pm, off));
        }
        if (lane == 0) {
            atomicAdd(&ch_sum[b * Cn + c], ps);
            atomicMax(&ch_max[b * Cn + c], fmap(pm));
        }
    }
    float4 av = make_float4(ssum.x * (1.f / Cn), ssum.y * (1.f / Cn),
                            ssum.z * (1.f / Cn), ssum.w * (1.f / Cn));
    *reinterpret_cast<float4*>(s_avg + (size_t)b * DHW + base) = av;
    *reinterpret_cast<float4*>(s_max + (size_t)b * DHW + base) = smax;
}

// ============================================================
// Kernel 2: channel-attention MLP.  ca[b,c] = sig(fc2(relu(fc1([avg,max]))))
// 1 block, 128 threads.
// ============================================================
__global__ __launch_bounds__(128) void ca_kernel(
    const float* __restrict__ ch_sum, const unsigned* __restrict__ ch_max,
    const float* __restrict__ fc1_w, const float* __restrict__ fc1_b,
    const float* __restrict__ fc2_w, const float* __restrict__ fc2_b,
    float* __restrict__ ca) {
    __shared__ float inp[64];
    __shared__ float h[128];
    const int t = threadIdx.x;
#pragma unroll 1
    for (int b = 0; b < Bn; ++b) {
        if (t < Cn) inp[t] = ch_sum[b * Cn + t] * (1.f / DHW);
        else if (t < 2 * Cn) inp[t] = funmap(ch_max[b * Cn + (t - Cn)]);
        __syncthreads();
        float acc = fc1_b[t];
#pragma unroll
        for (int k = 0; k < 64; ++k) acc += fc1_w[t * 64 + k] * inp[k];
        h[t] = fmaxf(acc, 0.f);
        __syncthreads();
        if (t < Cn) {
            float a2 = fc2_b[t];
#pragma unroll
            for (int k = 0; k < 128; ++k) a2 += fc2_w[t * 128 + k] * h[k];
            ca[b * Cn + t] = 1.f / (1.f + expf(-a2));
        }
        __syncthreads();
    }
}

// ============================================================
// Kernel 3: spatial attention, fully fused:
//   sa = sigmoid( conv1x1( relu( conv7x7x7([avg,max]) ) ) )
// Output tile 16(x) x 16(y) x 8(z); each thread owns one z-column of 8.
// Halo input tile in LDS: [2][14][22][22] = 54 KB.
// ============================================================
#define TZ 8
#define TY 16
#define TX 16
#define LZ (TZ + 6)
#define LY (TY + 6)
#define LX (TX + 6)
#define LDS_N (2 * LZ * LY * LX) /* 13552 */

__global__ __launch_bounds__(256) void conv_kernel(
    const float* __restrict__ s_avg, const float* __restrict__ s_max,
    const float* __restrict__ w1, const float* __restrict__ w2,
    float* __restrict__ sa) {
    __shared__ float sIn[LDS_N];
    const int bid = blockIdx.x;
    const int b = bid >> 7;       // 128 tiles per batch
    const int tile = bid & 127;
    const int tz = tile >> 4, ty = (tile >> 2) & 3, tx = tile & 3;
    const int z0 = tz * TZ, y0 = ty * TY, x0 = tx * TX;

    // --- load halo tile (zero-padded) ---
    for (int i = threadIdx.x; i < LDS_N; i += 256) {
        int xx = i % LX;
        int rem = i / LX;
        int yy = rem % LY;
        rem /= LY;
        int zz = rem % LZ;
        int ic = rem / LZ;
        int gz = z0 + zz - 3, gy = y0 + yy - 3, gx = x0 + xx - 3;
        float v = 0.f;
        if ((unsigned)gz < (unsigned)Dn && (unsigned)gy < (unsigned)Hn &&
            (unsigned)gx < (unsigned)Wn) {
            const float* src = ic ? s_max : s_avg;
            v = src[(size_t)b * DHW + (gz * Hn + gy) * Wn + gx];
        }
        sIn[i] = v;
    }
    __syncthreads();

    const int lx = threadIdx.x & 15, ly = threadIdx.x >> 4;
    float acc[4][TZ];
#pragma unroll
    for (int oc = 0; oc < 4; ++oc)
#pragma unroll
        for (int oz = 0; oz < TZ; ++oz) acc[oc][oz] = 0.f;

#pragma unroll 1
    for (int ic = 0; ic < 2; ++ic)
#pragma unroll 1
        for (int kh = 0; kh < 7; ++kh)
#pragma unroll 1
            for (int kw = 0; kw < 7; ++kw) {
                float incol[LZ];
#pragma unroll
                for (int zz = 0; zz < LZ; ++zz)
                    incol[zz] =
                        sIn[((ic * LZ + zz) * LY + (ly + kh)) * LX + (lx + kw)];
#pragma unroll
                for (int kd = 0; kd < 7; ++kd) {
#pragma unroll
                    for (int oc = 0; oc < 4; ++oc) {
                        // wave-uniform address -> scalar load
                        float w = w1[(((oc * 2 + ic) * 7 + kd) * 7 + kh) * 7 + kw];
#pragma unroll
                        for (int oz = 0; oz < TZ; ++oz)
                            acc[oc][oz] += incol[oz + kd] * w;
                    }
                }
            }

    const float c20 = w2[0], c21 = w2[1], c22 = w2[2], c23 = w2[3];
#pragma unroll
    for (int oz = 0; oz < TZ; ++oz) {
        float s = fmaxf(acc[0][oz], 0.f) * c20 + fmaxf(acc[1][oz], 0.f) * c21 +
                  fmaxf(acc[2][oz], 0.f) * c22 + fmaxf(acc[3][oz], 0.f) * c23;
        float sv = 1.f / (1.f + expf(-s));
        sa[(size_t)b * DHW + ((z0 + oz) * Hn + (y0 + ly)) * Wn + (x0 + lx)] = sv;
    }
}

// ============================================================
// Kernel 4: attention = sa * ca (broadcast), anti = 1 - attention.
// float4 grid-stride; writes both outputs.
// ============================================================
__global__ __launch_bounds__(256) void final_kernel(
    const float* __restrict__ sa, const float* __restrict__ ca,
    float4* __restrict__ out) {
    const int n4 = TOT / 4;  // 8388608
    const int stride = gridDim.x * blockDim.x;
    for (int i = blockIdx.x * blockDim.x + threadIdx.x; i < n4; i += stride) {
        const int bc = i >> 16;        // (i*4)/DHW
        const int sp4 = i & 65535;     // float4 index within DHW
        const int b = bc >> 5;
        const float cav = ca[bc];
        const float4 s4 =
            reinterpret_cast<const float4*>(sa + (size_t)b * DHW)[sp4];
        float4 att = make_float4(s4.x * cav, s4.y * cav, s4.z * cav, s4.w * cav);
        out[i] = att;
        out[n4 + i] =
            make_float4(1.f - att.x, 1.f - att.y, 1.f - att.z, 1.f - att.w);
    }
}

extern "C" void kernel_launch(void* const* d_in, const int* in_sizes, int n_in,
                              void* d_out, int out_size, void* d_ws,
                              size_t ws_size, hipStream_t stream) {
    const float* x = (const float*)d_in[0];
    const float* fc1_w = (const float*)d_in[1];
    const float* fc1_b = (const float*)d_in[2];
    const float* fc2_w = (const float*)d_in[3];
    const float* fc2_b = (const float*)d_in[4];
    const float* conv1_w = (const float*)d_in[5];
    const float* conv2_w = (const float*)d_in[6];

    float* ws = (float*)d_ws;
    float* s_avg = ws;                            // B*DHW
    float* s_max = ws + (size_t)Bn * DHW;         // B*DHW
    float* sa = ws + 2 * (size_t)Bn * DHW;        // B*DHW
    float* ch_sum = ws + 3 * (size_t)Bn * DHW;    // B*C
    unsigned* ch_max = (unsigned*)(ch_sum + Bn * Cn);  // B*C
    float* ca = (float*)(ch_max + Bn * Cn);       // B*C

    // zero channel accumulators (mapped-uint 0 == -inf)
    hipMemsetAsync(ch_sum, 0, 2 * Bn * Cn * sizeof(float), stream);

    reduce_kernel<<<Bn * (DHW / 1024), 256, 0, stream>>>(x, s_avg, s_max,
                                                         ch_sum, ch_max);
    ca_kernel<<<1, 128, 0, stream>>>(ch_sum, ch_max, fc1_w, fc1_b, fc2_w, fc2_b,
                                     ca);
    conv_kernel<<<Bn * 128, 256, 0, stream>>>(s_avg, s_max, conv1_w, conv2_w,
                                              sa);
    final_kernel<<<4096, 256, 0, stream>>>(sa, ca, (float4*)d_out);
}

// Round 2
// 201.744 us; speedup vs baseline: 2.7686x; 2.7686x over previous
//
#include <hip/hip_runtime.h>
#include <math.h>

#define Bn 4
#define Cn 32
#define Dn 64
#define Hn 64
#define Wn 64
#define DHW (Dn * Hn * Wn)      /* 262144 */
#define TOT (Bn * Cn * DHW)     /* 33554432 */

// ---- order-preserving float<->uint map for atomic max ----
__device__ __forceinline__ unsigned fmap(float f) {
    unsigned u = __float_as_uint(f);
    return (u & 0x80000000u) ? ~u : (u | 0x80000000u);
}
__device__ __forceinline__ float funmap(unsigned u) {
    return (u & 0x80000000u) ? __uint_as_float(u & 0x7fffffffu)
                             : __uint_as_float(~u);
}

// ============================================================
// Kernel 1: fused reductions.
//  - per (b, spatial): mean & max over C  -> s_avg, s_max  [B,DHW]
//  - per (b, c):      sum & max over DHW -> ch_sum, ch_max [B,C]
// Main loop is pure load+VALU (all cross-lane work hoisted to epilogue;
// per-channel partials live in registers, fully unrolled -> no scratch).
// Atomics: ONE 32-lane atomicAdd + ONE 32-lane atomicMax per block.
// grid: B * (DHW/1024) blocks, 256 threads, float4 per thread
// ============================================================
__global__ __launch_bounds__(256) void reduce_kernel(
    const float* __restrict__ x,
    float* __restrict__ s_avg, float* __restrict__ s_max,
    float* __restrict__ ch_sum, unsigned* __restrict__ ch_max) {
    const int blocks_per_b = DHW / 1024;  // 256
    const int b = blockIdx.x / blocks_per_b;
    const int chunk = blockIdx.x % blocks_per_b;
    const int base = chunk * 1024 + threadIdx.x * 4;
    const int lane = threadIdx.x & 63;
    const int wid = threadIdx.x >> 6;

    float4 ssum = make_float4(0.f, 0.f, 0.f, 0.f);
    float4 smax = make_float4(-INFINITY, -INFINITY, -INFINITY, -INFINITY);
    float tsum[Cn], tmax[Cn];

    const float* xp = x + (size_t)b * Cn * DHW + base;
#pragma unroll
    for (int c = 0; c < Cn; ++c) {
        const float4 v = *reinterpret_cast<const float4*>(xp + (size_t)c * DHW);
        ssum.x += v.x; ssum.y += v.y; ssum.z += v.z; ssum.w += v.w;
        smax.x = fmaxf(smax.x, v.x); smax.y = fmaxf(smax.y, v.y);
        smax.z = fmaxf(smax.z, v.z); smax.w = fmaxf(smax.w, v.w);
        tsum[c] = (v.x + v.y) + (v.z + v.w);
        tmax[c] = fmaxf(fmaxf(v.x, v.y), fmaxf(v.z, v.w));
    }

    // spatial outputs (coalesced float4)
    float4 av = make_float4(ssum.x * (1.f / Cn), ssum.y * (1.f / Cn),
                            ssum.z * (1.f / Cn), ssum.w * (1.f / Cn));
    *reinterpret_cast<float4*>(s_avg + (size_t)b * DHW + base) = av;
    *reinterpret_cast<float4*>(s_max + (size_t)b * DHW + base) = smax;

    // ---- block reduction of channel partials ----
    __shared__ float redS[4][Cn];
    __shared__ float redM[4][Cn];
#pragma unroll
    for (int c = 0; c < Cn; ++c) {
        float ps = tsum[c], pm = tmax[c];
#pragma unroll
        for (int off = 32; off; off >>= 1) {
            ps += __shfl_xor(ps, off);
            pm = fmaxf(pm, __shfl_xor(pm, off));
        }
        if (lane == 0) { redS[wid][c] = ps; redM[wid][c] = pm; }
    }
    __syncthreads();
    if (threadIdx.x < Cn) {
        const int c = threadIdx.x;
        float s = (redS[0][c] + redS[1][c]) + (redS[2][c] + redS[3][c]);
        float m = fmaxf(fmaxf(redM[0][c], redM[1][c]),
                        fmaxf(redM[2][c], redM[3][c]));
        atomicAdd(&ch_sum[b * Cn + c], s);
        atomicMax(&ch_max[b * Cn + c], fmap(m));
    }
}

// ============================================================
// Kernel 2: channel-attention MLP.  ca[b,c] = sig(fc2(relu(fc1([avg,max]))))
// 1 block, 128 threads.
// ============================================================
__global__ __launch_bounds__(128) void ca_kernel(
    const float* __restrict__ ch_sum, const unsigned* __restrict__ ch_max,
    const float* __restrict__ fc1_w, const float* __restrict__ fc1_b,
    const float* __restrict__ fc2_w, const float* __restrict__ fc2_b,
    float* __restrict__ ca) {
    __shared__ float inp[64];
    __shared__ float h[128];
    const int t = threadIdx.x;
#pragma unroll 1
    for (int b = 0; b < Bn; ++b) {
        if (t < Cn) inp[t] = ch_sum[b * Cn + t] * (1.f / DHW);
        else if (t < 2 * Cn) inp[t] = funmap(ch_max[b * Cn + (t - Cn)]);
        __syncthreads();
        float acc = fc1_b[t];
#pragma unroll
        for (int k = 0; k < 64; ++k) acc += fc1_w[t * 64 + k] * inp[k];
        h[t] = fmaxf(acc, 0.f);
        __syncthreads();
        if (t < Cn) {
            float a2 = fc2_b[t];
#pragma unroll
            for (int k = 0; k < 128; ++k) a2 += fc2_w[t * 128 + k] * h[k];
            ca[b * Cn + t] = 1.f / (1.f + expf(-a2));
        }
        __syncthreads();
    }
}

// ============================================================
// Kernel 3: spatial attention, fully fused:
//   sa = sigmoid( conv1x1( relu( conv7x7x7([avg,max]) ) ) )
// Output tile 16(x) x 16(y) x 8(z); each thread owns one z-column of 8.
// Halo input tile in LDS: [2][14][22][22] = 54 KB.
// ============================================================
#define TZ 8
#define TY 16
#define TX 16
#define LZ (TZ + 6)
#define LY (TY + 6)
#define LX (TX + 6)
#define LDS_N (2 * LZ * LY * LX) /* 13552 */

__global__ __launch_bounds__(256) void conv_kernel(
    const float* __restrict__ s_avg, const float* __restrict__ s_max,
    const float* __restrict__ w1, const float* __restrict__ w2,
    float* __restrict__ sa) {
    __shared__ float sIn[LDS_N];
    const int bid = blockIdx.x;
    const int b = bid >> 7;       // 128 tiles per batch
    const int tile = bid & 127;
    const int tz = tile >> 4, ty = (tile >> 2) & 3, tx = tile & 3;
    const int z0 = tz * TZ, y0 = ty * TY, x0 = tx * TX;

    // --- load halo tile (zero-padded) ---
    for (int i = threadIdx.x; i < LDS_N; i += 256) {
        int xx = i % LX;
        int rem = i / LX;
        int yy = rem % LY;
        rem /= LY;
        int zz = rem % LZ;
        int ic = rem / LZ;
        int gz = z0 + zz - 3, gy = y0 + yy - 3, gx = x0 + xx - 3;
        float v = 0.f;
        if ((unsigned)gz < (unsigned)Dn && (unsigned)gy < (unsigned)Hn &&
            (unsigned)gx < (unsigned)Wn) {
            const float* src = ic ? s_max : s_avg;
            v = src[(size_t)b * DHW + (gz * Hn + gy) * Wn + gx];
        }
        sIn[i] = v;
    }
    __syncthreads();

    const int lx = threadIdx.x & 15, ly = threadIdx.x >> 4;
    float acc[4][TZ];
#pragma unroll
    for (int oc = 0; oc < 4; ++oc)
#pragma unroll
        for (int oz = 0; oz < TZ; ++oz) acc[oc][oz] = 0.f;

#pragma unroll 1
    for (int ic = 0; ic < 2; ++ic)
#pragma unroll 1
        for (int kh = 0; kh < 7; ++kh)
#pragma unroll 1
            for (int kw = 0; kw < 7; ++kw) {
                float incol[LZ];
#pragma unroll
                for (int zz = 0; zz < LZ; ++zz)
                    incol[zz] =
                        sIn[((ic * LZ + zz) * LY + (ly + kh)) * LX + (lx + kw)];
#pragma unroll
                for (int kd = 0; kd < 7; ++kd) {
#pragma unroll
                    for (int oc = 0; oc < 4; ++oc) {
                        // wave-uniform address -> scalar load
                        float w = w1[(((oc * 2 + ic) * 7 + kd) * 7 + kh) * 7 + kw];
#pragma unroll
                        for (int oz = 0; oz < TZ; ++oz)
                            acc[oc][oz] += incol[oz + kd] * w;
                    }
                }
            }

    const float c20 = w2[0], c21 = w2[1], c22 = w2[2], c23 = w2[3];
#pragma unroll
    for (int oz = 0; oz < TZ; ++oz) {
        float s = fmaxf(acc[0][oz], 0.f) * c20 + fmaxf(acc[1][oz], 0.f) * c21 +
                  fmaxf(acc[2][oz], 0.f) * c22 + fmaxf(acc[3][oz], 0.f) * c23;
        float sv = 1.f / (1.f + expf(-s));
        sa[(size_t)b * DHW + ((z0 + oz) * Hn + (y0 + ly)) * Wn + (x0 + lx)] = sv;
    }
}

// ============================================================
// Kernel 4: attention = sa * ca (broadcast), anti = 1 - attention.
// float4 grid-stride; writes both outputs.
// ============================================================
__global__ __launch_bounds__(256) void final_kernel(
    const float* __restrict__ sa, const float* __restrict__ ca,
    float4* __restrict__ out) {
    const int n4 = TOT / 4;  // 8388608
    const int stride = gridDim.x * blockDim.x;
    for (int i = blockIdx.x * blockDim.x + threadIdx.x; i < n4; i += stride) {
        const int bc = i >> 16;        // (i*4)/DHW
        const int sp4 = i & 65535;     // float4 index within DHW
        const int b = bc >> 5;
        const float cav = ca[bc];
        const float4 s4 =
            reinterpret_cast<const float4*>(sa + (size_t)b * DHW)[sp4];
        float4 att = make_float4(s4.x * cav, s4.y * cav, s4.z * cav, s4.w * cav);
        out[i] = att;
        out[n4 + i] =
            make_float4(1.f - att.x, 1.f - att.y, 1.f - att.z, 1.f - att.w);
    }
}

extern "C" void kernel_launch(void* const* d_in, const int* in_sizes, int n_in,
                              void* d_out, int out_size, void* d_ws,
                              size_t ws_size, hipStream_t stream) {
    const float* x = (const float*)d_in[0];
    const float* fc1_w = (const float*)d_in[1];
    const float* fc1_b = (const float*)d_in[2];
    const float* fc2_w = (const float*)d_in[3];
    const float* fc2_b = (const float*)d_in[4];
    const float* conv1_w = (const float*)d_in[5];
    const float* conv2_w = (const float*)d_in[6];

    float* ws = (float*)d_ws;
    float* s_avg = ws;                            // B*DHW
    float* s_max = ws + (size_t)Bn * DHW;         // B*DHW
    float* sa = ws + 2 * (size_t)Bn * DHW;        // B*DHW
    float* ch_sum = ws + 3 * (size_t)Bn * DHW;    // B*C
    unsigned* ch_max = (unsigned*)(ch_sum + Bn * Cn);  // B*C
    float* ca = (float*)(ch_max + Bn * Cn);       // B*C

    // zero channel accumulators (mapped-uint 0 < fmap(any float) -> identity)
    hipMemsetAsync(ch_sum, 0, 2 * Bn * Cn * sizeof(float), stream);

    reduce_kernel<<<Bn * (DHW / 1024), 256, 0, stream>>>(x, s_avg, s_max,
                                                         ch_sum, ch_max);
    ca_kernel<<<1, 128, 0, stream>>>(ch_sum, ch_max, fc1_w, fc1_b, fc2_w, fc2_b,
                                     ca);
    conv_kernel<<<Bn * 128, 256, 0, stream>>>(s_avg, s_max, conv1_w, conv2_w,
                                              sa);
    final_kernel<<<4096, 256, 0, stream>>>(sa, ca, (float4*)d_out);
}

// Round 3
// 184.224 us; speedup vs baseline: 3.0319x; 1.0951x over previous
//
#include <hip/hip_runtime.h>
#include <math.h>

#define Bn 4
#define Cn 32
#define Dn 64
#define Hn 64
#define Wn 64
#define DHW (Dn * Hn * Wn)      /* 262144 */
#define TOT (Bn * Cn * DHW)     /* 33554432 */
#define NCHUNK 256              /* spatial chunks per batch in reduce */

// ============================================================
// Kernel 1: fused reductions (atomic-free).
//  - per (b, spatial): mean & max over C  -> s_avg, s_max  [B,DHW]
//  - per (b, c, chunk): partial sum & max -> part_sum/part_max [B,C,NCHUNK]
// grid: B*NCHUNK blocks, 256 threads, float4 per thread
// ============================================================
__global__ __launch_bounds__(256) void reduce_kernel(
    const float* __restrict__ x,
    float* __restrict__ s_avg, float* __restrict__ s_max,
    float* __restrict__ part_sum, float* __restrict__ part_max) {
    const int b = blockIdx.x / NCHUNK;
    const int chunk = blockIdx.x % NCHUNK;
    const int base = chunk * 1024 + threadIdx.x * 4;
    const int lane = threadIdx.x & 63;
    const int wid = threadIdx.x >> 6;

    float4 ssum = make_float4(0.f, 0.f, 0.f, 0.f);
    float4 smax = make_float4(-INFINITY, -INFINITY, -INFINITY, -INFINITY);
    float tsum[Cn], tmax[Cn];

    const float* xp = x + (size_t)b * Cn * DHW + base;
#pragma unroll
    for (int c = 0; c < Cn; ++c) {
        const float4 v = *reinterpret_cast<const float4*>(xp + (size_t)c * DHW);
        ssum.x += v.x; ssum.y += v.y; ssum.z += v.z; ssum.w += v.w;
        smax.x = fmaxf(smax.x, v.x); smax.y = fmaxf(smax.y, v.y);
        smax.z = fmaxf(smax.z, v.z); smax.w = fmaxf(smax.w, v.w);
        tsum[c] = (v.x + v.y) + (v.z + v.w);
        tmax[c] = fmaxf(fmaxf(v.x, v.y), fmaxf(v.z, v.w));
    }

    float4 av = make_float4(ssum.x * (1.f / Cn), ssum.y * (1.f / Cn),
                            ssum.z * (1.f / Cn), ssum.w * (1.f / Cn));
    *reinterpret_cast<float4*>(s_avg + (size_t)b * DHW + base) = av;
    *reinterpret_cast<float4*>(s_max + (size_t)b * DHW + base) = smax;

    __shared__ float redS[4][Cn];
    __shared__ float redM[4][Cn];
#pragma unroll
    for (int c = 0; c < Cn; ++c) {
        float ps = tsum[c], pm = tmax[c];
#pragma unroll
        for (int off = 32; off; off >>= 1) {
            ps += __shfl_xor(ps, off);
            pm = fmaxf(pm, __shfl_xor(pm, off));
        }
        if (lane == 0) { redS[wid][c] = ps; redM[wid][c] = pm; }
    }
    __syncthreads();
    if (threadIdx.x < Cn) {
        const int c = threadIdx.x;
        float s = (redS[0][c] + redS[1][c]) + (redS[2][c] + redS[3][c]);
        float m = fmaxf(fmaxf(redM[0][c], redM[1][c]),
                        fmaxf(redM[2][c], redM[3][c]));
        part_sum[(b * Cn + c) * NCHUNK + chunk] = s;
        part_max[(b * Cn + c) * NCHUNK + chunk] = m;
    }
}

// ============================================================
// Kernel 2: partial-reduce + channel-attention MLP. 1 block, 256 threads.
// phase 1: 256 threads each reduce one (which,b,c) over NCHUNK partials.
// phase 2: per batch, fc1 (128 thr) -> relu -> fc2 (32 thr) -> sigmoid.
// ============================================================
__global__ __launch_bounds__(256) void ca_kernel(
    const float* __restrict__ part_sum, const float* __restrict__ part_max,
    const float* __restrict__ fc1_w, const float* __restrict__ fc1_b,
    const float* __restrict__ fc2_w, const float* __restrict__ fc2_b,
    float* __restrict__ ca) {
    __shared__ float inpAll[Bn][64];
    __shared__ float h[128];
    const int t = threadIdx.x;
    {
        const int which = t >> 7;        // 0: sum, 1: max
        const int b = (t >> 5) & 3;
        const int c = t & 31;
        const float4* p4 = reinterpret_cast<const float4*>(
            (which ? part_max : part_sum) + (b * Cn + c) * NCHUNK);
        if (which == 0) {
            float acc = 0.f;
#pragma unroll
            for (int i = 0; i < NCHUNK / 4; ++i) {
                float4 v = p4[i];
                acc += (v.x + v.y) + (v.z + v.w);
            }
            inpAll[b][c] = acc * (1.f / DHW);
        } else {
            float m = -INFINITY;
#pragma unroll
            for (int i = 0; i < NCHUNK / 4; ++i) {
                float4 v = p4[i];
                m = fmaxf(m, fmaxf(fmaxf(v.x, v.y), fmaxf(v.z, v.w)));
            }
            inpAll[b][Cn + c] = m;
        }
    }
    __syncthreads();
#pragma unroll 1
    for (int b = 0; b < Bn; ++b) {
        if (t < 128) {
            float acc = fc1_b[t];
#pragma unroll
            for (int k = 0; k < 64; ++k) acc += fc1_w[t * 64 + k] * inpAll[b][k];
            h[t] = fmaxf(acc, 0.f);
        }
        __syncthreads();
        if (t < Cn) {
            float a2 = fc2_b[t];
#pragma unroll
            for (int k = 0; k < 128; ++k) a2 += fc2_w[t * 128 + k] * h[k];
            ca[b * Cn + t] = 1.f / (1.f + expf(-a2));
        }
        __syncthreads();
    }
}

// ============================================================
// Kernel 3: fully fused spatial attention + output:
//   sa = sigmoid(conv1x1(relu(conv7x7x7([avg,max]))))
//   out[b,c,...]     = sa * ca[b,c]
//   out[TOT + ...]   = 1 - sa * ca[b,c]
// Tile: full-x 64 (coalesced writes) x 4(y) x 8(z). Thread = one z-column.
// Two input channels processed sequentially through ONE 38 KB halo buffer.
// sv staged in 8 KB LDS -> epilogue writes 1KB-contiguous float4 per wave.
// ============================================================
#define TZc 8
#define TYc 4
#define LXc (Wn + 6)   /* 70 */
#define LYc (TYc + 6)  /* 10 */
#define LZc (TZc + 6)  /* 14 */
#define HALO_N (LZc * LYc * LXc) /* 9800 */

__global__ __launch_bounds__(256) void conv_kernel(
    const float* __restrict__ s_avg, const float* __restrict__ s_max,
    const float* __restrict__ w1, const float* __restrict__ w2,
    const float* __restrict__ ca, float* __restrict__ out) {
    __shared__ float sIn[HALO_N];            // 38.3 KB
    __shared__ float sv_s[TZc * TYc * Wn];   // 2048 floats, 8 KB
    __shared__ float ca_s[Cn];

    const int bid = blockIdx.x;
    const int b = bid >> 7;           // 128 tiles per batch
    const int tile = bid & 127;
    const int tz = tile >> 4, ty = tile & 15;
    const int z0 = tz * TZc, y0 = ty * TYc;
    const int lx = threadIdx.x & 63, ly = threadIdx.x >> 6;

    if (threadIdx.x < Cn) ca_s[threadIdx.x] = ca[b * Cn + threadIdx.x];

    float acc[4][TZc];
#pragma unroll
    for (int oc = 0; oc < 4; ++oc)
#pragma unroll
        for (int oz = 0; oz < TZc; ++oz) acc[oc][oz] = 0.f;

#pragma unroll 1
    for (int ic = 0; ic < 2; ++ic) {
        __syncthreads();  // protect sIn reuse
        const float* src = (ic ? s_max : s_avg) + (size_t)b * DHW;
        for (int i = threadIdx.x; i < HALO_N; i += 256) {
            const int xx = i % LXc;
            const int rem = i / LXc;
            const int yy = rem % LYc;
            const int zz = rem / LYc;
            const int gz = z0 + zz - 3, gy = y0 + yy - 3, gx = xx - 3;
            float v = 0.f;
            if ((unsigned)gz < (unsigned)Dn && (unsigned)gy < (unsigned)Hn &&
                (unsigned)gx < (unsigned)Wn)
                v = src[(gz * Hn + gy) * Wn + gx];
            sIn[i] = v;
        }
        __syncthreads();
#pragma unroll 1
        for (int kh = 0; kh < 7; ++kh)
#pragma unroll 1
            for (int kw = 0; kw < 7; ++kw) {
                float incol[LZc];
#pragma unroll
                for (int zz = 0; zz < LZc; ++zz)
                    incol[zz] = sIn[(zz * LYc + (ly + kh)) * LXc + (lx + kw)];
#pragma unroll
                for (int kd = 0; kd < 7; ++kd)
#pragma unroll
                    for (int oc = 0; oc < 4; ++oc) {
                        // wave-uniform address -> scalar load
                        float w = w1[(((oc * 2 + ic) * 7 + kd) * 7 + kh) * 7 + kw];
#pragma unroll
                        for (int oz = 0; oz < TZc; ++oz)
                            acc[oc][oz] += incol[oz + kd] * w;
                    }
            }
    }

    const float c20 = w2[0], c21 = w2[1], c22 = w2[2], c23 = w2[3];
#pragma unroll
    for (int oz = 0; oz < TZc; ++oz) {
        float s = fmaxf(acc[0][oz], 0.f) * c20 + fmaxf(acc[1][oz], 0.f) * c21 +
                  fmaxf(acc[2][oz], 0.f) * c22 + fmaxf(acc[3][oz], 0.f) * c23;
        sv_s[oz * 256 + threadIdx.x] = 1.f / (1.f + expf(-s));
    }
    __syncthreads();

    // epilogue: each wave writes one (c,oz) 1KB-contiguous segment per iter
    const int wv = threadIdx.x >> 6, ln = threadIdx.x & 63;
    const float4* sv4 = reinterpret_cast<const float4*>(sv_s);
    float4* out4 = reinterpret_cast<float4*>(out);
    const size_t totq = TOT / 4;
#pragma unroll 1
    for (int combo = wv; combo < Cn * TZc; combo += 4) {
        const int c = combo >> 3, oz = combo & 7;
        const float cav = ca_s[c];
        const float4 v = sv4[oz * 64 + ln];
        const float4 att =
            make_float4(v.x * cav, v.y * cav, v.z * cav, v.w * cav);
        const size_t off =
            (((size_t)(b * Cn + c) * DHW + (size_t)(z0 + oz) * (Hn * Wn) +
              (size_t)y0 * Wn) >> 2) + ln;
        out4[off] = att;
        out4[totq + off] =
            make_float4(1.f - att.x, 1.f - att.y, 1.f - att.z, 1.f - att.w);
    }
}

extern "C" void kernel_launch(void* const* d_in, const int* in_sizes, int n_in,
                              void* d_out, int out_size, void* d_ws,
                              size_t ws_size, hipStream_t stream) {
    const float* x = (const float*)d_in[0];
    const float* fc1_w = (const float*)d_in[1];
    const float* fc1_b = (const float*)d_in[2];
    const float* fc2_w = (const float*)d_in[3];
    const float* fc2_b = (const float*)d_in[4];
    const float* conv1_w = (const float*)d_in[5];
    const float* conv2_w = (const float*)d_in[6];

    float* ws = (float*)d_ws;
    float* s_avg = ws;                               // B*DHW
    float* s_max = s_avg + (size_t)Bn * DHW;         // B*DHW
    float* part_sum = s_max + (size_t)Bn * DHW;      // B*C*NCHUNK
    float* part_max = part_sum + Bn * Cn * NCHUNK;   // B*C*NCHUNK
    float* ca = part_max + Bn * Cn * NCHUNK;         // B*C

    reduce_kernel<<<Bn * NCHUNK, 256, 0, stream>>>(x, s_avg, s_max, part_sum,
                                                   part_max);
    ca_kernel<<<1, 256, 0, stream>>>(part_sum, part_max, fc1_w, fc1_b, fc2_w,
                                     fc2_b, ca);
    conv_kernel<<<Bn * 128, 256, 0, stream>>>(s_avg, s_max, conv1_w, conv2_w,
                                              ca, (float*)d_out);
}

// Round 4
// 179.175 us; speedup vs baseline: 3.1173x; 1.0282x over previous
//
#include <hip/hip_runtime.h>
#include <math.h>

#define Bn 4
#define Cn 32
#define Dn 64
#define Hn 64
#define Wn 64
#define DHW (Dn * Hn * Wn)      /* 262144 */
#define TOT (Bn * Cn * DHW)     /* 33554432 */
#define NCHUNK 256              /* spatial chunks per batch in reduce */

// ============================================================
// Kernel 1: fused reductions (atomic-free).
//  - per (b, spatial): mean & max over C  -> s_avg, s_max  [B,DHW]
//  - per (b, c, chunk): partial sum & max -> part_sum/part_max [B,C,NCHUNK]
// grid: B*NCHUNK blocks, 256 threads, float4 per thread
// ============================================================
__global__ __launch_bounds__(256) void reduce_kernel(
    const float* __restrict__ x,
    float* __restrict__ s_avg, float* __restrict__ s_max,
    float* __restrict__ part_sum, float* __restrict__ part_max) {
    const int b = blockIdx.x / NCHUNK;
    const int chunk = blockIdx.x % NCHUNK;
    const int base = chunk * 1024 + threadIdx.x * 4;
    const int lane = threadIdx.x & 63;
    const int wid = threadIdx.x >> 6;

    float4 ssum = make_float4(0.f, 0.f, 0.f, 0.f);
    float4 smax = make_float4(-INFINITY, -INFINITY, -INFINITY, -INFINITY);
    float tsum[Cn], tmax[Cn];

    const float* xp = x + (size_t)b * Cn * DHW + base;
#pragma unroll
    for (int c = 0; c < Cn; ++c) {
        const float4 v = *reinterpret_cast<const float4*>(xp + (size_t)c * DHW);
        ssum.x += v.x; ssum.y += v.y; ssum.z += v.z; ssum.w += v.w;
        smax.x = fmaxf(smax.x, v.x); smax.y = fmaxf(smax.y, v.y);
        smax.z = fmaxf(smax.z, v.z); smax.w = fmaxf(smax.w, v.w);
        tsum[c] = (v.x + v.y) + (v.z + v.w);
        tmax[c] = fmaxf(fmaxf(v.x, v.y), fmaxf(v.z, v.w));
    }

    float4 av = make_float4(ssum.x * (1.f / Cn), ssum.y * (1.f / Cn),
                            ssum.z * (1.f / Cn), ssum.w * (1.f / Cn));
    *reinterpret_cast<float4*>(s_avg + (size_t)b * DHW + base) = av;
    *reinterpret_cast<float4*>(s_max + (size_t)b * DHW + base) = smax;

    __shared__ float redS[4][Cn];
    __shared__ float redM[4][Cn];
#pragma unroll
    for (int c = 0; c < Cn; ++c) {
        float ps = tsum[c], pm = tmax[c];
#pragma unroll
        for (int off = 32; off; off >>= 1) {
            ps += __shfl_xor(ps, off);
            pm = fmaxf(pm, __shfl_xor(pm, off));
        }
        if (lane == 0) { redS[wid][c] = ps; redM[wid][c] = pm; }
    }
    __syncthreads();
    if (threadIdx.x < Cn) {
        const int c = threadIdx.x;
        float s = (redS[0][c] + redS[1][c]) + (redS[2][c] + redS[3][c]);
        float m = fmaxf(fmaxf(redM[0][c], redM[1][c]),
                        fmaxf(redM[2][c], redM[3][c]));
        part_sum[(b * Cn + c) * NCHUNK + chunk] = s;
        part_max[(b * Cn + c) * NCHUNK + chunk] = m;
    }
}

// ============================================================
// Kernel 2: everything else, fused.
//  Per block (tile 64x * 2y * 8z of one batch):
//   - redundant channel-MLP from L2-resident partials -> ca_s[32]
//   - sa = sigmoid(conv1x1(relu(conv7x7x7([avg,max]))))
//   - out = sa*ca, 1-sa*ca  (268 MB streamed)
//  1024 blocks, 35.7 KB LDS -> 4 blocks/CU for phase overlap.
//  Thread = half-z-column: (zh, ly, lx) covers oz in [zh*4, zh*4+4).
// ============================================================
#define TZc 8
#define TYc 2
#define LXc (Wn + 6)   /* 70 */
#define LYc (TYc + 6)  /* 8  */
#define LZc (TZc + 6)  /* 14 */
#define HALO_N (LZc * LYc * LXc) /* 7840 */

__global__ __launch_bounds__(256) void conv_kernel(
    const float* __restrict__ part_sum, const float* __restrict__ part_max,
    const float* __restrict__ fc1_w, const float* __restrict__ fc1_b,
    const float* __restrict__ fc2_w, const float* __restrict__ fc2_b,
    const float* __restrict__ s_avg, const float* __restrict__ s_max,
    const float* __restrict__ w1, const float* __restrict__ w2,
    float* __restrict__ out) {
    __shared__ float sIn[HALO_N];                  // 31.4 KB
    __shared__ float sv_s[TZc * TYc * Wn];         // 1024 floats, 4 KB
    __shared__ float inp_s[64];
    __shared__ float h_s[128];
    __shared__ float ca_s[Cn];

    const int t = threadIdx.x;
    const int bid = blockIdx.x;
    const int b = bid >> 8;            // 256 tiles per batch
    const int tile = bid & 255;
    const int tz = tile >> 5, ty = tile & 31;
    const int z0 = tz * TZc, y0 = ty * TYc;

    // ---- channel-attention MLP (redundant per block; inputs L2-resident) ----
    if (t < 64) {
        const int which = t >> 5, c = t & 31;
        const float4* p4 = reinterpret_cast<const float4*>(
            (which ? part_max : part_sum) + (b * Cn + c) * NCHUNK);
        if (which == 0) {
            float acc = 0.f;
#pragma unroll
            for (int i = 0; i < NCHUNK / 4; ++i) {
                float4 v = p4[i];
                acc += (v.x + v.y) + (v.z + v.w);
            }
            inp_s[c] = acc * (1.f / DHW);
        } else {
            float m = -INFINITY;
#pragma unroll
            for (int i = 0; i < NCHUNK / 4; ++i) {
                float4 v = p4[i];
                m = fmaxf(m, fmaxf(fmaxf(v.x, v.y), fmaxf(v.z, v.w)));
            }
            inp_s[Cn + c] = m;
        }
    }
    __syncthreads();
    if (t < 128) {
        float acc = fc1_b[t];
#pragma unroll
        for (int k = 0; k < 64; ++k) acc += fc1_w[t * 64 + k] * inp_s[k];
        h_s[t] = fmaxf(acc, 0.f);
    }
    __syncthreads();
    if (t < Cn) {
        float a2 = fc2_b[t];
#pragma unroll
        for (int k = 0; k < 128; ++k) a2 += fc2_w[t * 128 + k] * h_s[k];
        ca_s[t] = 1.f / (1.f + expf(-a2));
    }

    // ---- conv: thread owns (zh, ly, lx) half-z-column of 4 outputs ----
    const int lx = t & 63, ly = (t >> 6) & 1, zh = t >> 7;

    float acc[4][4];  // [oc][oz2]
#pragma unroll
    for (int oc = 0; oc < 4; ++oc)
#pragma unroll
        for (int o = 0; o < 4; ++o) acc[oc][o] = 0.f;

#pragma unroll 1
    for (int ic = 0; ic < 2; ++ic) {
        __syncthreads();  // protect sIn reuse (also orders MLP phase on ic=0)
        const float* src = (ic ? s_max : s_avg) + (size_t)b * DHW;
        for (int i = t; i < HALO_N; i += 256) {
            const int xx = i % LXc;
            const int rem = i / LXc;
            const int yy = rem % LYc;
            const int zz = rem / LYc;
            const int gz = z0 + zz - 3, gy = y0 + yy - 3, gx = xx - 3;
            float v = 0.f;
            if ((unsigned)gz < (unsigned)Dn && (unsigned)gy < (unsigned)Hn &&
                (unsigned)gx < (unsigned)Wn)
                v = src[(gz * Hn + gy) * Wn + gx];
            sIn[i] = v;
        }
        __syncthreads();
#pragma unroll 1
        for (int kh = 0; kh < 7; ++kh)
#pragma unroll 1
            for (int kw = 0; kw < 7; ++kw) {
                float incol[10];
#pragma unroll
                for (int s = 0; s < 10; ++s)
                    incol[s] =
                        sIn[((zh * 4 + s) * LYc + (ly + kh)) * LXc + (lx + kw)];
#pragma unroll
                for (int kd = 0; kd < 7; ++kd)
#pragma unroll
                    for (int oc = 0; oc < 4; ++oc) {
                        // wave-uniform address -> scalar load
                        float w = w1[(((oc * 2 + ic) * 7 + kd) * 7 + kh) * 7 + kw];
#pragma unroll
                        for (int o = 0; o < 4; ++o)
                            acc[oc][o] += incol[o + kd] * w;
                    }
            }
    }

    const float c20 = w2[0], c21 = w2[1], c22 = w2[2], c23 = w2[3];
#pragma unroll
    for (int o = 0; o < 4; ++o) {
        float s = fmaxf(acc[0][o], 0.f) * c20 + fmaxf(acc[1][o], 0.f) * c21 +
                  fmaxf(acc[2][o], 0.f) * c22 + fmaxf(acc[3][o], 0.f) * c23;
        sv_s[((zh * 4 + o) * TYc + ly) * Wn + lx] = 1.f / (1.f + expf(-s));
    }
    __syncthreads();

    // ---- epilogue: wave writes one (c,oz) 2-row (512B) segment per iter ----
    const int wv = t >> 6, ln = t & 63;
    const float2* sv2 = reinterpret_cast<const float2*>(sv_s);
    float2* out2 = reinterpret_cast<float2*>(out);
    const size_t totq2 = TOT / 2;
#pragma unroll 1
    for (int combo = wv; combo < Cn * TZc; combo += 4) {
        const int c = combo >> 3, oz = combo & 7;
        const float cav = ca_s[c];
        const float2 v = sv2[oz * (TYc * Wn / 2) + ln];
        const float2 att = make_float2(v.x * cav, v.y * cav);
        const size_t off = (((size_t)(b * Cn + c) * DHW +
                             (size_t)(z0 + oz) * (Hn * Wn) +
                             (size_t)y0 * Wn) >> 1) + ln;
        out2[off] = att;
        out2[totq2 + off] = make_float2(1.f - att.x, 1.f - att.y);
    }
}

extern "C" void kernel_launch(void* const* d_in, const int* in_sizes, int n_in,
                              void* d_out, int out_size, void* d_ws,
                              size_t ws_size, hipStream_t stream) {
    const float* x = (const float*)d_in[0];
    const float* fc1_w = (const float*)d_in[1];
    const float* fc1_b = (const float*)d_in[2];
    const float* fc2_w = (const float*)d_in[3];
    const float* fc2_b = (const float*)d_in[4];
    const float* conv1_w = (const float*)d_in[5];
    const float* conv2_w = (const float*)d_in[6];

    float* ws = (float*)d_ws;
    float* s_avg = ws;                               // B*DHW
    float* s_max = s_avg + (size_t)Bn * DHW;         // B*DHW
    float* part_sum = s_max + (size_t)Bn * DHW;      // B*C*NCHUNK
    float* part_max = part_sum + Bn * Cn * NCHUNK;   // B*C*NCHUNK

    reduce_kernel<<<Bn * NCHUNK, 256, 0, stream>>>(x, s_avg, s_max, part_sum,
                                                   part_max);
    conv_kernel<<<Bn * 256, 256, 0, stream>>>(part_sum, part_max, fc1_w, fc1_b,
                                              fc2_w, fc2_b, s_avg, s_max,
                                              conv1_w, conv2_w, (float*)d_out);
}